// Round 2
// baseline (363.789 us; speedup 1.0000x reference)
//
#include <hip/hip_runtime.h>
#include <math.h>

#define BB 8
#define HH 512
#define WW 1024
#define HW (HH * WW)          // 524288 = 2^19
#define NPIX (BB * HW)        // 4194304
#define NSEG 16               // segments 1..16 (0 skipped)
#define SUPPRESS 0.1f

// ---------------- pass 1: boundary, sobel, smooth, segment moments ----------------
// Block = 256 threads, tile = 2 rows x 1024 cols. LDS-staged stencil.
__global__ __launch_bounds__(256) void pass1_kernel(
    const float* __restrict__ flow,
    const int*   __restrict__ masks,
    const float* __restrict__ images,
    double* __restrict__ moments,     // [B][16][14]
    double* __restrict__ scal,        // [0]=sum_dx [1]=sum_dy [2]=Sb [3]=Sbf
    unsigned* __restrict__ maxfg_bits)
{
    // rows: sm/smask hold global rows h0-1 .. h0+2 (4 rows); su/sv/sg hold h0 .. h0+2 (3 rows)
    __shared__ float         sm[4][1032];    // flow magnitude, data at col 4..1027, zero halo at 3 and 1028
    __shared__ unsigned char smask[4][1032]; // masks (u8), data at col 4..1027, replicated halo
    __shared__ float         su[3][1024];
    __shared__ float         sv[3][1024];
    __shared__ float         sg[3][1024];
    __shared__ float         bins[NSEG * 14];
    __shared__ float         wred[4][5];

    const int tid = threadIdx.x;
    const int lane = tid & 63;
    const long long base = (long long)blockIdx.x * 2048;  // 2 rows per block
    const int b  = (int)(base >> 19);
    const int h0 = (int)((base & (HW - 1)) >> 10);

    const float* fu = flow + (long long)b * (2LL * HW);
    const float* fv = fu + HW;
    const int*   mk = masks + (long long)b * HW;
    const float* i0 = images + (long long)b * (3LL * HW);
    const float* i1 = i0 + HW;
    const float* i2 = i1 + HW;

    for (int t = tid; t < NSEG * 14; t += 256) bins[t] = 0.f;

    // ---------- phase A: cooperative staging ----------
    const int c4 = tid * 4;
    #pragma unroll
    for (int r = 0; r < 4; ++r) {
        const int gr = h0 - 1 + r;
        const int mr = gr < 0 ? 0 : (gr > HH - 1 ? HH - 1 : gr);   // replicate-clamp for masks
        const int4 mv = *(const int4*)&mk[mr * WW + c4];
        uchar4 mb;
        mb.x = (unsigned char)mv.x; mb.y = (unsigned char)mv.y;
        mb.z = (unsigned char)mv.z; mb.w = (unsigned char)mv.w;
        *(uchar4*)&smask[r][4 + c4] = mb;

        float4 u4 = make_float4(0.f, 0.f, 0.f, 0.f);
        float4 v4 = make_float4(0.f, 0.f, 0.f, 0.f);
        if (gr >= 0 && gr <= HH - 1) {
            u4 = *(const float4*)&fu[gr * WW + c4];
            v4 = *(const float4*)&fv[gr * WW + c4];
        }
        float4 m4;
        m4.x = sqrtf(u4.x * u4.x + v4.x * v4.x);
        m4.y = sqrtf(u4.y * u4.y + v4.y * v4.y);
        m4.z = sqrtf(u4.z * u4.z + v4.z * v4.z);
        m4.w = sqrtf(u4.w * u4.w + v4.w * v4.w);
        *(float4*)&sm[r][4 + c4] = m4;
        if (r >= 1) {
            *(float4*)&su[r - 1][c4] = u4;
            *(float4*)&sv[r - 1][c4] = v4;
        }
    }
    #pragma unroll
    for (int r = 0; r < 3; ++r) {
        const int gr = h0 + r;
        float4 g4 = make_float4(0.f, 0.f, 0.f, 0.f);
        if (gr <= HH - 1) {
            const float4 a = *(const float4*)&i0[gr * WW + c4];
            const float4 bq = *(const float4*)&i1[gr * WW + c4];
            const float4 c = *(const float4*)&i2[gr * WW + c4];
            g4.x = (a.x + bq.x + c.x) * (1.f / 3.f);
            g4.y = (a.y + bq.y + c.y) * (1.f / 3.f);
            g4.z = (a.z + bq.z + c.z) * (1.f / 3.f);
            g4.w = (a.w + bq.w + c.w) * (1.f / 3.f);
        }
        *(float4*)&sg[r][c4] = g4;
    }
    // halos (computed from global directly; visible after the single sync below)
    if (tid < 4) {
        const int gr = h0 - 1 + tid;
        const int mr = gr < 0 ? 0 : (gr > HH - 1 ? HH - 1 : gr);
        smask[tid][3]    = (unsigned char)mk[mr * WW + 0];
        smask[tid][1028] = (unsigned char)mk[mr * WW + WW - 1];
        sm[tid][3] = 0.f;
        sm[tid][1028] = 0.f;
    }
    __syncthreads();

    // ---------- phase B: compute ----------
    float a_dx = 0.f, a_dy = 0.f, a_sb = 0.f, a_sbf = 0.f, mfg = 0.f;

    #pragma unroll
    for (int it = 0; it < 8; ++it) {
        const int idx = it * 256 + tid;    // 0..2047
        const int lr = idx >> 10;          // 0 or 1
        const int w  = idx & 1023;
        const int h  = h0 + lr;
        const int cc = 4 + w;

        const int segc = smask[lr + 1][cc];
        int bnd = (smask[lr][cc - 1] != segc) | (smask[lr][cc] != segc) |
                  (smask[lr][cc + 1] != segc) |
                  (smask[lr + 1][cc - 1] != segc) | (smask[lr + 1][cc + 1] != segc) |
                  (smask[lr + 2][cc - 1] != segc) | (smask[lr + 2][cc] != segc) |
                  (smask[lr + 2][cc + 1] != segc);

        // sobel (zero-padded), center row = lr+1
        const float t00 = sm[lr][cc - 1],     t01 = sm[lr][cc],     t02 = sm[lr][cc + 1];
        const float t10 = sm[lr + 1][cc - 1],                       t12 = sm[lr + 1][cc + 1];
        const float t20 = sm[lr + 2][cc - 1], t21 = sm[lr + 2][cc], t22 = sm[lr + 2][cc + 1];
        const float fgx = (t02 - t00) + 2.f * (t12 - t10) + (t22 - t20);
        const float fgy = (t20 + 2.f * t21 + t22) - (t00 + 2.f * t01 + t02);
        const float fgraw = fabsf(fgx) + fabsf(fgy);
        mfg = fmaxf(mfg, fgraw);
        if (bnd) { a_sb += 1.f; a_sbf += fgraw; }

        const float u = su[lr][w], v = sv[lr][w];
        const float g0 = sg[lr][w];
        if (w < WW - 1) {
            const float wgt = expf(-fabsf(sg[lr][w + 1] - g0) * 10.f) * (bnd ? SUPPRESS : 1.f);
            a_dx += (fabsf(su[lr][w + 1] - u) + fabsf(sv[lr][w + 1] - v)) * wgt;
        }
        if (h < HH - 1) {
            const float wgt = expf(-fabsf(sg[lr + 1][w] - g0) * 10.f) * (bnd ? SUPPRESS : 1.f);
            a_dy += (fabsf(su[lr + 1][w] - u) + fabsf(sv[lr + 1][w] - v)) * wgt;
        }

        if (segc != 0) {
            float* bp = &bins[(segc - 1) * 14];
            const float x = (float)w, y = (float)h;
            atomicAdd(&bp[0], 1.f);
            atomicAdd(&bp[1], x);
            atomicAdd(&bp[2], y);
            atomicAdd(&bp[3], x * x);
            atomicAdd(&bp[4], x * y);
            atomicAdd(&bp[5], y * y);
            atomicAdd(&bp[6], u);
            atomicAdd(&bp[7], v);
            atomicAdd(&bp[8], u * u);
            atomicAdd(&bp[9], v * v);
            atomicAdd(&bp[10], x * u);
            atomicAdd(&bp[11], y * u);
            atomicAdd(&bp[12], x * v);
            atomicAdd(&bp[13], y * v);
        }
    }

    // block-reduce the five scalars
    for (int off = 32; off > 0; off >>= 1) {
        a_dx += __shfl_down(a_dx, off);
        a_dy += __shfl_down(a_dy, off);
        a_sb += __shfl_down(a_sb, off);
        a_sbf += __shfl_down(a_sbf, off);
        mfg = fmaxf(mfg, __shfl_down(mfg, off));
    }
    if (lane == 0) {
        const int wv = tid >> 6;
        wred[wv][0] = a_dx; wred[wv][1] = a_dy; wred[wv][2] = a_sb;
        wred[wv][3] = a_sbf; wred[wv][4] = mfg;
    }
    __syncthreads();
    if (tid == 0) {
        float dx = 0.f, dy = 0.f, sb = 0.f, sbf = 0.f, mf = 0.f;
        for (int i = 0; i < 4; ++i) {
            dx += wred[i][0]; dy += wred[i][1]; sb += wred[i][2];
            sbf += wred[i][3]; mf = fmaxf(mf, wred[i][4]);
        }
        atomicAdd(&scal[0], (double)dx);
        atomicAdd(&scal[1], (double)dy);
        atomicAdd(&scal[2], (double)sb);
        atomicAdd(&scal[3], (double)sbf);
        atomicMax(maxfg_bits, __float_as_uint(mf));  // nonneg floats: bit-monotone
    }
    if (tid < NSEG * 14)
        atomicAdd(&moments[b * (NSEG * 14) + tid], (double)bins[tid]);
}

// ---------------- solve: 3x3 normal equations + object variance ----------------
__global__ __launch_bounds__(128) void solve_kernel(
    const double* __restrict__ moments,
    float* __restrict__ params,   // [128][6]
    int* __restrict__ valid,      // [128]
    float* __restrict__ out)
{
    const int i = threadIdx.x;    // (b, seg-1)
    const double* m = &moments[i * 14];
    const double n = m[0];
    const int vh = (n >= 100.0) ? 1 : 0;
    float p[6] = {0.f, 0.f, 0.f, 0.f, 0.f, 0.f};
    if (vh) {
        double A[3][3] = {{m[3], m[4], m[1]},
                          {m[4], m[5], m[2]},
                          {m[1], m[2], n}};
        double Bm[3][2] = {{m[10], m[12]},
                           {m[11], m[13]},
                           {m[6],  m[7]}};
        for (int k = 0; k < 3; ++k) {
            int piv = k; double mx = fabs(A[k][k]);
            for (int r = k + 1; r < 3; ++r) {
                double a = fabs(A[r][k]);
                if (a > mx) { mx = a; piv = r; }
            }
            if (piv != k) {
                for (int c = 0; c < 3; ++c) { double t = A[k][c]; A[k][c] = A[piv][c]; A[piv][c] = t; }
                for (int c = 0; c < 2; ++c) { double t = Bm[k][c]; Bm[k][c] = Bm[piv][c]; Bm[piv][c] = t; }
            }
            const double inv = 1.0 / A[k][k];
            for (int r = k + 1; r < 3; ++r) {
                const double f = A[r][k] * inv;
                for (int c = k; c < 3; ++c) A[r][c] -= f * A[k][c];
                Bm[r][0] -= f * Bm[k][0];
                Bm[r][1] -= f * Bm[k][1];
            }
        }
        double X[3][2];
        for (int c = 0; c < 2; ++c) {
            X[2][c] = Bm[2][c] / A[2][2];
            X[1][c] = (Bm[1][c] - A[1][2] * X[2][c]) / A[1][1];
            X[0][c] = (Bm[0][c] - A[0][1] * X[1][c] - A[0][2] * X[2][c]) / A[0][0];
        }
        p[0] = (float)X[0][0]; p[1] = (float)X[1][0]; p[2] = (float)X[2][0];
        p[3] = (float)X[0][1]; p[4] = (float)X[1][1]; p[5] = (float)X[2][1];
    }
    valid[i] = vh;
    for (int c = 0; c < 6; ++c) params[i * 6 + c] = p[c];

    // object variance (unbiased)
    const int vv = (n >= 50.0) ? 1 : 0;
    double var = 0.0;
    if (vv) {
        const double ns = (n > 2.0) ? n : 2.0;
        const double var_u = (m[8] - m[6] * m[6] / ns) / (ns - 1.0);
        const double var_v = (m[9] - m[7] * m[7] / ns) / (ns - 1.0);
        var = var_u + var_v;
    }
    __shared__ double svar[128];
    __shared__ int scnt[128];
    svar[i] = var; scnt[i] = vv;
    __syncthreads();
    for (int s = 64; s > 0; s >>= 1) {
        if (i < s) { svar[i] += svar[i + s]; scnt[i] += scnt[i + s]; }
        __syncthreads();
    }
    if (i == 0) out[2] = (float)(svar[0] / (double)(scnt[0] > 1 ? scnt[0] : 1));
}

// ---------------- pass 2: per-pixel affine-fit residuals (vectorized) ----------------
__global__ __launch_bounds__(256) void pass2_kernel(
    const float* __restrict__ flow,
    const int*   __restrict__ masks,
    const float* __restrict__ params,
    const int*   __restrict__ valid,
    double* __restrict__ res_sum)
{
    __shared__ float rbins[NSEG];
    __shared__ float sp[NSEG * 6];
    __shared__ int   sv_[NSEG];

    const long long base = (long long)blockIdx.x * 4096;
    const int b      = (int)(base >> 19);
    const int hwbase = (int)(base & (HW - 1));

    if (threadIdx.x < NSEG) { rbins[threadIdx.x] = 0.f; sv_[threadIdx.x] = valid[b * NSEG + threadIdx.x]; }
    if (threadIdx.x < NSEG * 6) sp[threadIdx.x] = params[b * NSEG * 6 + threadIdx.x];
    __syncthreads();

    const float* fu = flow + (long long)b * (2LL * HW);
    const float* fv = fu + HW;
    const int*   mk = masks + (long long)b * HW;

    #pragma unroll
    for (int it = 0; it < 4; ++it) {
        const int i4 = hwbase + it * 1024 + threadIdx.x * 4;
        const int4   m4 = *(const int4*)&mk[i4];
        const float4 u4 = *(const float4*)&fu[i4];
        const float4 v4 = *(const float4*)&fv[i4];
        const int segs[4] = {m4.x, m4.y, m4.z, m4.w};
        const float us[4] = {u4.x, u4.y, u4.z, u4.w};
        const float vs[4] = {v4.x, v4.y, v4.z, v4.w};
        #pragma unroll
        for (int j = 0; j < 4; ++j) {
            const int segc = segs[j];
            if (segc == 0) continue;
            if (!sv_[segc - 1]) continue;
            const float* pf = &sp[(segc - 1) * 6];
            const int hw = i4 + j;
            const float x = (float)(hw & 1023), y = (float)(hw >> 10);
            const float du = us[j] - (x * pf[0] + y * pf[1] + pf[2]);
            const float dv = vs[j] - (x * pf[3] + y * pf[4] + pf[5]);
            atomicAdd(&rbins[segc - 1], sqrtf(du * du + dv * dv));
        }
    }
    __syncthreads();
    if (threadIdx.x < NSEG)
        atomicAdd(&res_sum[b * NSEG + threadIdx.x], (double)rbins[threadIdx.x]);
}

// ---------------- finalize: homog, sharp, smooth ----------------
__global__ __launch_bounds__(128) void final_kernel(
    const double* __restrict__ moments,
    const double* __restrict__ res_sum,
    const int*    __restrict__ valid,
    const double* __restrict__ scal,
    const unsigned* __restrict__ maxfg_bits,
    float* __restrict__ out)
{
    const int i = threadIdx.x;
    const double n = moments[i * 14];
    const int vh = valid[i];
    const double rm = vh ? res_sum[i] / (n > 1.0 ? n : 1.0) : 0.0;
    __shared__ double sr[128];
    __shared__ int sc[128];
    sr[i] = rm; sc[i] = vh;
    __syncthreads();
    for (int s = 64; s > 0; s >>= 1) {
        if (i < s) { sr[i] += sr[i + s]; sc[i] += sc[i + s]; }
        __syncthreads();
    }
    if (i == 0) {
        out[0] = (float)(sr[0] / (double)(sc[0] > 1 ? sc[0] : 1));
        const double sb = scal[2], sbf = scal[3];
        const double maxfg = (double)__uint_as_float(*maxfg_bits);
        const double maxb = (sb > 0.0) ? 1.0 : 0.0;
        out[1] = (float)((sb - sbf / (maxfg + 1e-6)) / (maxb + 1e-6) / (double)NPIX);
        const double smooth = scal[0] / (double)(2LL * BB * HH * (WW - 1)) +
                              scal[1] / (double)(2LL * BB * (HH - 1) * WW);
        out[3] = (float)smooth;
    }
}

extern "C" void kernel_launch(void* const* d_in, const int* in_sizes, int n_in,
                              void* d_out, int out_size, void* d_ws, size_t ws_size,
                              hipStream_t stream)
{
    const float* flow   = (const float*)d_in[0];
    const int*   masks  = (const int*)d_in[1];
    const float* images = (const float*)d_in[2];
    float* out = (float*)d_out;

    char* ws = (char*)d_ws;
    // layout: moments f64[1792] | res_sum f64[128] | scal f64[4] | maxfg u32 | params f32[768] | valid i32[128]
    double*   moments = (double*)(ws);             // 0     .. 14336
    double*   res_sum = (double*)(ws + 14336);     // 14336 .. 15360
    double*   scal    = (double*)(ws + 15360);     // 15360 .. 15392
    unsigned* maxfg   = (unsigned*)(ws + 15392);   // 15392 .. 15396
    float*    params  = (float*)(ws + 15396);      // 15396 .. 18468
    int*      valid   = (int*)(ws + 18468);        // 18468 .. 18980

    hipMemsetAsync(d_ws, 0, 19456, stream);

    pass1_kernel<<<dim3(NPIX / 2048), dim3(256), 0, stream>>>(
        flow, masks, images, moments, scal, maxfg);
    solve_kernel<<<dim3(1), dim3(128), 0, stream>>>(moments, params, valid, out);
    pass2_kernel<<<dim3(NPIX / 4096), dim3(256), 0, stream>>>(
        flow, masks, params, valid, res_sum);
    final_kernel<<<dim3(1), dim3(128), 0, stream>>>(
        moments, res_sum, valid, scal, maxfg, out);
}

// Round 3
// 360.530 us; speedup vs baseline: 1.0090x; 1.0090x over previous
//
#include <hip/hip_runtime.h>
#include <math.h>

#define BB 8
#define HH 512
#define WW 1024
#define HW (HH * WW)          // 524288 = 2^19
#define NPIX (BB * HW)        // 4194304
#define NSEG 16               // segments 1..16 (0 skipped)
#define SUPPRESS 0.1f

#define NREP 8                // LDS bin replicas (pass1)
#define RSTRIDE 225           // odd word stride: bank shift of 1 per replica
#define NREP2 16              // replicas (pass2)
#define RSTRIDE2 17

// ---------------- pass 1: boundary, sobel, smooth, segment moments ----------------
// Block = 256 threads, tile = 2 rows x 1024 cols. LDS-staged stencil.
// Segment moments go to 8-way replicated LDS bins to kill same-address
// ds_add serialization (the round-1/2 bottleneck).
__global__ __launch_bounds__(256) void pass1_kernel(
    const float* __restrict__ flow,
    const int*   __restrict__ masks,
    const float* __restrict__ images,
    double* __restrict__ moments,     // [B][16][14]
    double* __restrict__ scal,        // [0]=sum_dx [1]=sum_dy [2]=Sb [3]=Sbf
    unsigned* __restrict__ maxfg_bits)
{
    __shared__ float         sm[4][1032];    // flow magnitude, data at col 4..1027, zero halo at 3/1028
    __shared__ unsigned char smask[4][1032]; // masks (u8), data at col 4..1027, replicated halo
    __shared__ float         su[3][1024];
    __shared__ float         sv[3][1024];
    __shared__ float         sg[3][1024];
    __shared__ float         binsR[NREP * RSTRIDE];   // 8 replicas x (16 segs x 14 moments)
    __shared__ float         wred[4][5];

    const int tid = threadIdx.x;
    const int lane = tid & 63;
    const long long base = (long long)blockIdx.x * 2048;  // 2 rows per block
    const int b  = (int)(base >> 19);
    const int h0 = (int)((base & (HW - 1)) >> 10);

    const float* fu = flow + (long long)b * (2LL * HW);
    const float* fv = fu + HW;
    const int*   mk = masks + (long long)b * HW;
    const float* i0 = images + (long long)b * (3LL * HW);
    const float* i1 = i0 + HW;
    const float* i2 = i1 + HW;

    for (int t = tid; t < NREP * RSTRIDE; t += 256) binsR[t] = 0.f;

    // ---------- phase A: cooperative staging ----------
    const int c4 = tid * 4;
    #pragma unroll
    for (int r = 0; r < 4; ++r) {
        const int gr = h0 - 1 + r;
        const int mr = gr < 0 ? 0 : (gr > HH - 1 ? HH - 1 : gr);   // replicate-clamp for masks
        const int4 mv = *(const int4*)&mk[mr * WW + c4];
        uchar4 mb;
        mb.x = (unsigned char)mv.x; mb.y = (unsigned char)mv.y;
        mb.z = (unsigned char)mv.z; mb.w = (unsigned char)mv.w;
        *(uchar4*)&smask[r][4 + c4] = mb;

        float4 u4 = make_float4(0.f, 0.f, 0.f, 0.f);
        float4 v4 = make_float4(0.f, 0.f, 0.f, 0.f);
        if (gr >= 0 && gr <= HH - 1) {
            u4 = *(const float4*)&fu[gr * WW + c4];
            v4 = *(const float4*)&fv[gr * WW + c4];
        }
        float4 m4;
        m4.x = sqrtf(u4.x * u4.x + v4.x * v4.x);
        m4.y = sqrtf(u4.y * u4.y + v4.y * v4.y);
        m4.z = sqrtf(u4.z * u4.z + v4.z * v4.z);
        m4.w = sqrtf(u4.w * u4.w + v4.w * v4.w);
        *(float4*)&sm[r][4 + c4] = m4;
        if (r >= 1) {
            *(float4*)&su[r - 1][c4] = u4;
            *(float4*)&sv[r - 1][c4] = v4;
        }
    }
    #pragma unroll
    for (int r = 0; r < 3; ++r) {
        const int gr = h0 + r;
        float4 g4 = make_float4(0.f, 0.f, 0.f, 0.f);
        if (gr <= HH - 1) {
            const float4 a = *(const float4*)&i0[gr * WW + c4];
            const float4 bq = *(const float4*)&i1[gr * WW + c4];
            const float4 c = *(const float4*)&i2[gr * WW + c4];
            g4.x = (a.x + bq.x + c.x) * (1.f / 3.f);
            g4.y = (a.y + bq.y + c.y) * (1.f / 3.f);
            g4.z = (a.z + bq.z + c.z) * (1.f / 3.f);
            g4.w = (a.w + bq.w + c.w) * (1.f / 3.f);
        }
        *(float4*)&sg[r][c4] = g4;
    }
    // halos
    if (tid < 4) {
        const int gr = h0 - 1 + tid;
        const int mr = gr < 0 ? 0 : (gr > HH - 1 ? HH - 1 : gr);
        smask[tid][3]    = (unsigned char)mk[mr * WW + 0];
        smask[tid][1028] = (unsigned char)mk[mr * WW + WW - 1];
        sm[tid][3] = 0.f;
        sm[tid][1028] = 0.f;
    }
    __syncthreads();

    // ---------- phase B: compute ----------
    float a_dx = 0.f, a_dy = 0.f, a_sb = 0.f, a_sbf = 0.f, mfg = 0.f;
    const int repbase = (lane & (NREP - 1)) * RSTRIDE;

    #pragma unroll
    for (int it = 0; it < 8; ++it) {
        const int idx = it * 256 + tid;    // 0..2047
        const int lr = idx >> 10;          // 0 or 1
        const int w  = idx & 1023;
        const int h  = h0 + lr;
        const int cc = 4 + w;

        const int segc = smask[lr + 1][cc];
        int bnd = (smask[lr][cc - 1] != segc) | (smask[lr][cc] != segc) |
                  (smask[lr][cc + 1] != segc) |
                  (smask[lr + 1][cc - 1] != segc) | (smask[lr + 1][cc + 1] != segc) |
                  (smask[lr + 2][cc - 1] != segc) | (smask[lr + 2][cc] != segc) |
                  (smask[lr + 2][cc + 1] != segc);

        // sobel (zero-padded), center row = lr+1
        const float t00 = sm[lr][cc - 1],     t01 = sm[lr][cc],     t02 = sm[lr][cc + 1];
        const float t10 = sm[lr + 1][cc - 1],                       t12 = sm[lr + 1][cc + 1];
        const float t20 = sm[lr + 2][cc - 1], t21 = sm[lr + 2][cc], t22 = sm[lr + 2][cc + 1];
        const float fgx = (t02 - t00) + 2.f * (t12 - t10) + (t22 - t20);
        const float fgy = (t20 + 2.f * t21 + t22) - (t00 + 2.f * t01 + t02);
        const float fgraw = fabsf(fgx) + fabsf(fgy);
        mfg = fmaxf(mfg, fgraw);
        if (bnd) { a_sb += 1.f; a_sbf += fgraw; }

        const float u = su[lr][w], v = sv[lr][w];
        const float g0 = sg[lr][w];
        if (w < WW - 1) {
            const float wgt = expf(-fabsf(sg[lr][w + 1] - g0) * 10.f) * (bnd ? SUPPRESS : 1.f);
            a_dx += (fabsf(su[lr][w + 1] - u) + fabsf(sv[lr][w + 1] - v)) * wgt;
        }
        if (h < HH - 1) {
            const float wgt = expf(-fabsf(sg[lr + 1][w] - g0) * 10.f) * (bnd ? SUPPRESS : 1.f);
            a_dy += (fabsf(su[lr + 1][w] - u) + fabsf(sv[lr + 1][w] - v)) * wgt;
        }

        if (segc != 0) {
            float* bp = &binsR[repbase + (segc - 1) * 14];
            const float x = (float)w, y = (float)h;
            atomicAdd(&bp[0], 1.f);
            atomicAdd(&bp[1], x);
            atomicAdd(&bp[2], y);
            atomicAdd(&bp[3], x * x);
            atomicAdd(&bp[4], x * y);
            atomicAdd(&bp[5], y * y);
            atomicAdd(&bp[6], u);
            atomicAdd(&bp[7], v);
            atomicAdd(&bp[8], u * u);
            atomicAdd(&bp[9], v * v);
            atomicAdd(&bp[10], x * u);
            atomicAdd(&bp[11], y * u);
            atomicAdd(&bp[12], x * v);
            atomicAdd(&bp[13], y * v);
        }
    }

    // block-reduce the five scalars
    for (int off = 32; off > 0; off >>= 1) {
        a_dx += __shfl_down(a_dx, off);
        a_dy += __shfl_down(a_dy, off);
        a_sb += __shfl_down(a_sb, off);
        a_sbf += __shfl_down(a_sbf, off);
        mfg = fmaxf(mfg, __shfl_down(mfg, off));
    }
    if (lane == 0) {
        const int wv = tid >> 6;
        wred[wv][0] = a_dx; wred[wv][1] = a_dy; wred[wv][2] = a_sb;
        wred[wv][3] = a_sbf; wred[wv][4] = mfg;
    }
    __syncthreads();
    if (tid == 0) {
        float dx = 0.f, dy = 0.f, sb = 0.f, sbf = 0.f, mf = 0.f;
        for (int i = 0; i < 4; ++i) {
            dx += wred[i][0]; dy += wred[i][1]; sb += wred[i][2];
            sbf += wred[i][3]; mf = fmaxf(mf, wred[i][4]);
        }
        atomicAdd(&scal[0], (double)dx);
        atomicAdd(&scal[1], (double)dy);
        atomicAdd(&scal[2], (double)sb);
        atomicAdd(&scal[3], (double)sbf);
        atomicMax(maxfg_bits, __float_as_uint(mf));  // nonneg floats: bit-monotone
    }
    if (tid < NSEG * 14) {
        float s = 0.f;
        #pragma unroll
        for (int r = 0; r < NREP; ++r) s += binsR[r * RSTRIDE + tid];
        atomicAdd(&moments[b * (NSEG * 14) + tid], (double)s);
    }
}

// ---------------- solve: 3x3 normal equations + object variance ----------------
__global__ __launch_bounds__(128) void solve_kernel(
    const double* __restrict__ moments,
    float* __restrict__ params,   // [128][6]
    int* __restrict__ valid,      // [128]
    float* __restrict__ out)
{
    const int i = threadIdx.x;    // (b, seg-1)
    const double* m = &moments[i * 14];
    const double n = m[0];
    const int vh = (n >= 100.0) ? 1 : 0;
    float p[6] = {0.f, 0.f, 0.f, 0.f, 0.f, 0.f};
    if (vh) {
        double A[3][3] = {{m[3], m[4], m[1]},
                          {m[4], m[5], m[2]},
                          {m[1], m[2], n}};
        double Bm[3][2] = {{m[10], m[12]},
                           {m[11], m[13]},
                           {m[6],  m[7]}};
        for (int k = 0; k < 3; ++k) {
            int piv = k; double mx = fabs(A[k][k]);
            for (int r = k + 1; r < 3; ++r) {
                double a = fabs(A[r][k]);
                if (a > mx) { mx = a; piv = r; }
            }
            if (piv != k) {
                for (int c = 0; c < 3; ++c) { double t = A[k][c]; A[k][c] = A[piv][c]; A[piv][c] = t; }
                for (int c = 0; c < 2; ++c) { double t = Bm[k][c]; Bm[k][c] = Bm[piv][c]; Bm[piv][c] = t; }
            }
            const double inv = 1.0 / A[k][k];
            for (int r = k + 1; r < 3; ++r) {
                const double f = A[r][k] * inv;
                for (int c = k; c < 3; ++c) A[r][c] -= f * A[k][c];
                Bm[r][0] -= f * Bm[k][0];
                Bm[r][1] -= f * Bm[k][1];
            }
        }
        double X[3][2];
        for (int c = 0; c < 2; ++c) {
            X[2][c] = Bm[2][c] / A[2][2];
            X[1][c] = (Bm[1][c] - A[1][2] * X[2][c]) / A[1][1];
            X[0][c] = (Bm[0][c] - A[0][1] * X[1][c] - A[0][2] * X[2][c]) / A[0][0];
        }
        p[0] = (float)X[0][0]; p[1] = (float)X[1][0]; p[2] = (float)X[2][0];
        p[3] = (float)X[0][1]; p[4] = (float)X[1][1]; p[5] = (float)X[2][1];
    }
    valid[i] = vh;
    for (int c = 0; c < 6; ++c) params[i * 6 + c] = p[c];

    // object variance (unbiased)
    const int vv = (n >= 50.0) ? 1 : 0;
    double var = 0.0;
    if (vv) {
        const double ns = (n > 2.0) ? n : 2.0;
        const double var_u = (m[8] - m[6] * m[6] / ns) / (ns - 1.0);
        const double var_v = (m[9] - m[7] * m[7] / ns) / (ns - 1.0);
        var = var_u + var_v;
    }
    __shared__ double svar[128];
    __shared__ int scnt[128];
    svar[i] = var; scnt[i] = vv;
    __syncthreads();
    for (int s = 64; s > 0; s >>= 1) {
        if (i < s) { svar[i] += svar[i + s]; scnt[i] += scnt[i + s]; }
        __syncthreads();
    }
    if (i == 0) out[2] = (float)(svar[0] / (double)(scnt[0] > 1 ? scnt[0] : 1));
}

// ---------------- pass 2: per-pixel affine-fit residuals (vectorized) ----------------
__global__ __launch_bounds__(256) void pass2_kernel(
    const float* __restrict__ flow,
    const int*   __restrict__ masks,
    const float* __restrict__ params,
    const int*   __restrict__ valid,
    double* __restrict__ res_sum)
{
    __shared__ float rbinsR[NREP2 * RSTRIDE2];
    __shared__ float sp[NSEG * 6];
    __shared__ int   sv_[NSEG];

    const long long base = (long long)blockIdx.x * 4096;
    const int b      = (int)(base >> 19);
    const int hwbase = (int)(base & (HW - 1));

    for (int t = threadIdx.x; t < NREP2 * RSTRIDE2; t += 256) rbinsR[t] = 0.f;
    if (threadIdx.x < NSEG) sv_[threadIdx.x] = valid[b * NSEG + threadIdx.x];
    if (threadIdx.x < NSEG * 6) sp[threadIdx.x] = params[b * NSEG * 6 + threadIdx.x];
    __syncthreads();

    const float* fu = flow + (long long)b * (2LL * HW);
    const float* fv = fu + HW;
    const int*   mk = masks + (long long)b * HW;
    const int repbase = (threadIdx.x & (NREP2 - 1)) * RSTRIDE2;

    #pragma unroll
    for (int it = 0; it < 4; ++it) {
        const int i4 = hwbase + it * 1024 + threadIdx.x * 4;
        const int4   m4 = *(const int4*)&mk[i4];
        const float4 u4 = *(const float4*)&fu[i4];
        const float4 v4 = *(const float4*)&fv[i4];
        const int segs[4] = {m4.x, m4.y, m4.z, m4.w};
        const float us[4] = {u4.x, u4.y, u4.z, u4.w};
        const float vs[4] = {v4.x, v4.y, v4.z, v4.w};
        #pragma unroll
        for (int j = 0; j < 4; ++j) {
            const int segc = segs[j];
            if (segc == 0) continue;
            if (!sv_[segc - 1]) continue;
            const float* pf = &sp[(segc - 1) * 6];
            const int hw = i4 + j;
            const float x = (float)(hw & 1023), y = (float)(hw >> 10);
            const float du = us[j] - (x * pf[0] + y * pf[1] + pf[2]);
            const float dv = vs[j] - (x * pf[3] + y * pf[4] + pf[5]);
            atomicAdd(&rbinsR[repbase + (segc - 1)], sqrtf(du * du + dv * dv));
        }
    }
    __syncthreads();
    if (threadIdx.x < NSEG) {
        float s = 0.f;
        #pragma unroll
        for (int r = 0; r < NREP2; ++r) s += rbinsR[r * RSTRIDE2 + threadIdx.x];
        atomicAdd(&res_sum[b * NSEG + threadIdx.x], (double)s);
    }
}

// ---------------- finalize: homog, sharp, smooth ----------------
__global__ __launch_bounds__(128) void final_kernel(
    const double* __restrict__ moments,
    const double* __restrict__ res_sum,
    const int*    __restrict__ valid,
    const double* __restrict__ scal,
    const unsigned* __restrict__ maxfg_bits,
    float* __restrict__ out)
{
    const int i = threadIdx.x;
    const double n = moments[i * 14];
    const int vh = valid[i];
    const double rm = vh ? res_sum[i] / (n > 1.0 ? n : 1.0) : 0.0;
    __shared__ double sr[128];
    __shared__ int sc[128];
    sr[i] = rm; sc[i] = vh;
    __syncthreads();
    for (int s = 64; s > 0; s >>= 1) {
        if (i < s) { sr[i] += sr[i + s]; sc[i] += sc[i + s]; }
        __syncthreads();
    }
    if (i == 0) {
        out[0] = (float)(sr[0] / (double)(sc[0] > 1 ? sc[0] : 1));
        const double sb = scal[2], sbf = scal[3];
        const double maxfg = (double)__uint_as_float(*maxfg_bits);
        const double maxb = (sb > 0.0) ? 1.0 : 0.0;
        out[1] = (float)((sb - sbf / (maxfg + 1e-6)) / (maxb + 1e-6) / (double)NPIX);
        const double smooth = scal[0] / (double)(2LL * BB * HH * (WW - 1)) +
                              scal[1] / (double)(2LL * BB * (HH - 1) * WW);
        out[3] = (float)smooth;
    }
}

extern "C" void kernel_launch(void* const* d_in, const int* in_sizes, int n_in,
                              void* d_out, int out_size, void* d_ws, size_t ws_size,
                              hipStream_t stream)
{
    const float* flow   = (const float*)d_in[0];
    const int*   masks  = (const int*)d_in[1];
    const float* images = (const float*)d_in[2];
    float* out = (float*)d_out;

    char* ws = (char*)d_ws;
    // layout: moments f64[1792] | res_sum f64[128] | scal f64[4] | maxfg u32 | params f32[768] | valid i32[128]
    double*   moments = (double*)(ws);             // 0     .. 14336
    double*   res_sum = (double*)(ws + 14336);     // 14336 .. 15360
    double*   scal    = (double*)(ws + 15360);     // 15360 .. 15392
    unsigned* maxfg   = (unsigned*)(ws + 15392);   // 15392 .. 15396
    float*    params  = (float*)(ws + 15396);      // 15396 .. 18468
    int*      valid   = (int*)(ws + 18468);        // 18468 .. 18980

    hipMemsetAsync(d_ws, 0, 19456, stream);

    pass1_kernel<<<dim3(NPIX / 2048), dim3(256), 0, stream>>>(
        flow, masks, images, moments, scal, maxfg);
    solve_kernel<<<dim3(1), dim3(128), 0, stream>>>(moments, params, valid, out);
    pass2_kernel<<<dim3(NPIX / 4096), dim3(256), 0, stream>>>(
        flow, masks, params, valid, res_sum);
    final_kernel<<<dim3(1), dim3(128), 0, stream>>>(
        moments, res_sum, valid, scal, maxfg, out);
}